// Round 3
// baseline (2938.825 us; speedup 1.0000x reference)
//
#include <hip/hip_runtime.h>

#define B 8
#define D 512
#define T 2048
#define K 8192

#define TM 64
#define TN 128
#define TD 32

// d_ws layout (bytes): x2[B*T] f32 at 0 (64KB), e2[K] f32 at 65536 (32KB)
#define WS_X2 0
#define WS_E2 65536

// ---- x2[p] = numpy-pairwise f32 sum of squares over d (n=512 tree) --------
// tree: ((B0+B1)+(B2+B3)), each B = 128-block 8-accumulator unroll
__global__ __launch_bounds__(256)
void vq_x2_kernel(const float* __restrict__ lat, float* __restrict__ x2g) {
#pragma clang fp contract(off)
    int p = blockIdx.x * 256 + threadIdx.x;      // p in [0, B*T)
    int b = p / T, t = p % T;
    const float* base = lat + (size_t)b * D * T + t;   // stride T along d
    float blk[4];
#pragma unroll
    for (int q = 0; q < 4; q++) {
        float r[8];
#pragma unroll
        for (int j = 0; j < 8; j++) {
            float v = base[(size_t)(q * 128 + j) * T];
            r[j] = __fmul_rn(v, v);
        }
        for (int i = 8; i < 128; i += 8) {
#pragma unroll
            for (int j = 0; j < 8; j++) {
                float v = base[(size_t)(q * 128 + i + j) * T];
                r[j] = __fadd_rn(r[j], __fmul_rn(v, v));
            }
        }
        blk[q] = __fadd_rn(__fadd_rn(__fadd_rn(r[0], r[1]), __fadd_rn(r[2], r[3])),
                           __fadd_rn(__fadd_rn(r[4], r[5]), __fadd_rn(r[6], r[7])));
    }
    x2g[p] = __fadd_rn(__fadd_rn(blk[0], blk[1]), __fadd_rn(blk[2], blk[3]));
}

// ---- e2[k] = numpy-pairwise f32 sum of squares over d (contiguous row) ----
__global__ __launch_bounds__(256)
void vq_e2_kernel(const float* __restrict__ emb, float* __restrict__ e2g) {
#pragma clang fp contract(off)
    int k = blockIdx.x * 256 + threadIdx.x;      // k in [0, K)
    const float* base = emb + (size_t)k * D;
    float blk[4];
#pragma unroll
    for (int q = 0; q < 4; q++) {
        float r[8];
#pragma unroll
        for (int j = 0; j < 8; j++) {
            float v = base[q * 128 + j];
            r[j] = __fmul_rn(v, v);
        }
        for (int i = 8; i < 128; i += 8) {
#pragma unroll
            for (int j = 0; j < 8; j++) {
                float v = base[q * 128 + i + j];
                r[j] = __fadd_rn(r[j], __fmul_rn(v, v));
            }
        }
        blk[q] = __fadd_rn(__fadd_rn(__fadd_rn(r[0], r[1]), __fadd_rn(r[2], r[3])),
                           __fadd_rn(__fadd_rn(r[4], r[5]), __fadd_rn(r[6], r[7])));
    }
    e2g[k] = __fadd_rn(__fadd_rn(blk[0], blk[1]), __fadd_rn(blk[2], blk[3]));
}

// ---- main: sequential-f32 dots (einsum replica) + quantized d2 + argmin ----
__global__ __launch_bounds__(256)
void vq_main_kernel(const float* __restrict__ latents,
                    const float* __restrict__ emb,
                    const float* __restrict__ x2g,
                    const float* __restrict__ e2g,
                    float* __restrict__ out) {
#pragma clang fp contract(off)
    __shared__ __align__(16) float xs[TD][TM];       // 8 KB
    __shared__ __align__(16) float es[TD][TN + 4];   // 16.9 KB
    __shared__ float e2s[TN];
    __shared__ float x2s[TM];
    __shared__ int ids_s[TM];
    __shared__ __align__(16) float gbuf[64][65];     // 16.6 KB

    const int tid = threadIdx.x;
    const int tn = tid & 15;       // n-dimension thread (16)
    const int tm = tid >> 4;       // m-dimension thread (16)
    const int m0 = blockIdx.x * TM;
    const int b = m0 / T;
    const int t0 = m0 % T;
    const float* lat = latents + (size_t)b * D * T + t0;

    if (tid < TM) x2s[tid] = x2g[m0 + tid];   // visible after first barrier

    float minv[4];
    int mini[4];
#pragma unroll
    for (int i = 0; i < 4; i++) { minv[i] = 3.4e38f; mini[i] = 0; }

    for (int k0 = 0; k0 < K; k0 += TN) {
        __syncthreads();                     // prev ktile readers done (also fences x2s)
        if (tid < TN) e2s[tid] = e2g[k0 + tid];

        // sequential f32 accumulators over the FULL d=0..511 (einsum order)
        float s[4][8];
#pragma unroll
        for (int i = 0; i < 4; i++)
#pragma unroll
            for (int j = 0; j < 8; j++) s[i][j] = 0.0f;

        for (int d0 = 0; d0 < D; d0 += TD) {
            if (d0) __syncthreads();
            // stage x tile: xs[dd][tt] = lat[(d0+dd)*T + tt]  (coalesced along t)
#pragma unroll
            for (int i = 0; i < 8; i++) {
                int idx = tid + i * 256;
                int dd = idx >> 6, tt = idx & 63;
                xs[dd][tt] = lat[(size_t)(d0 + dd) * T + tt];
            }
            // stage e tile transposed: es[dd][nn] = emb[(k0+nn)*D + d0+dd]
#pragma unroll
            for (int i = 0; i < 16; i++) {
                int idx = tid + i * 256;
                int nn = idx >> 5, dd = idx & 31;
                es[dd][nn] = emb[(size_t)(k0 + nn) * D + d0 + dd];
            }
            __syncthreads();

#pragma unroll
            for (int d = 0; d < TD; d++) {   // global d = d0+d ascending
                float4 xr = *(const float4*)&xs[d][tm * 4];
                float4 ea = *(const float4*)&es[d][tn * 4];
                float4 eb = *(const float4*)&es[d][64 + tn * 4];
                float xv[4] = {xr.x, xr.y, xr.z, xr.w};
                float ev[8] = {ea.x, ea.y, ea.z, ea.w, eb.x, eb.y, eb.z, eb.w};
#pragma unroll
                for (int i = 0; i < 4; i++)
#pragma unroll
                    for (int j = 0; j < 8; j++)
                        s[i][j] = __fadd_rn(s[i][j], __fmul_rn(xv[i], ev[j]));
            }
        }

        // d2 = fl(fl(x2 - fl(2*xe)) + e2), argmin first-index
#pragma unroll
        for (int i = 0; i < 4; i++) {
            float x2v = x2s[tm * 4 + i];
#pragma unroll
            for (int j = 0; j < 8; j++) {
                int col = (j < 4) ? (tn * 4 + j) : (64 + tn * 4 + (j - 4));
                float s2 = __fadd_rn(s[i][j], s[i][j]);       // 2*xe (exact)
                float tmp = __fsub_rn(x2v, s2);
                float dist = __fadd_rn(tmp, e2s[col]);
                int kk = k0 + col;
                if (dist < minv[i]) { minv[i] = dist; mini[i] = kk; }
            }
        }
    }

    // reduce argmin across the 16 tn-threads (lowest value, then lowest index)
#pragma unroll
    for (int i = 0; i < 4; i++) {
        float v1 = minv[i];
        int i1 = mini[i];
#pragma unroll
        for (int off = 1; off < 16; off <<= 1) {
            float ov = __shfl_xor(v1, off);
            int oi = __shfl_xor(i1, off);
            if (ov < v1 || (ov == v1 && oi < i1)) { v1 = ov; i1 = oi; }
        }
        if (tn == 0) ids_s[tm * 4 + i] = i1;
    }
    __syncthreads();

    // gather + transpose: out[b][d][t0+tt] = emb[ids_s[tt]][d]
    float* outb = out + (size_t)b * D * T + t0;
    for (int d0 = 0; d0 < D; d0 += 64) {
        if (d0) __syncthreads();
#pragma unroll
        for (int i = 0; i < 16; i++) {
            int idx = tid + i * 256;
            int tt = idx >> 6, dd = idx & 63;
            gbuf[tt][dd] = emb[(size_t)ids_s[tt] * D + d0 + dd];
        }
        __syncthreads();
#pragma unroll
        for (int i = 0; i < 16; i++) {
            int idx = tid + i * 256;
            int dd = idx >> 6, tt = idx & 63;
            outb[(size_t)(d0 + dd) * T + tt] = gbuf[tt][dd];
        }
    }
}

extern "C" void kernel_launch(void* const* d_in, const int* in_sizes, int n_in,
                              void* d_out, int out_size, void* d_ws, size_t ws_size,
                              hipStream_t stream) {
    const float* latents = (const float*)d_in[0];   // [B, D, T]
    const float* emb     = (const float*)d_in[1];   // [K, D]
    float* out = (float*)d_out;                      // [B, D, T]
    char* ws = (char*)d_ws;
    float* x2g = (float*)(ws + WS_X2);
    float* e2g = (float*)(ws + WS_E2);

    hipLaunchKernelGGL(vq_x2_kernel, dim3((B * T) / 256), dim3(256), 0, stream,
                       latents, x2g);
    hipLaunchKernelGGL(vq_e2_kernel, dim3(K / 256), dim3(256), 0, stream,
                       emb, e2g);
    hipLaunchKernelGGL(vq_main_kernel, dim3((B * T) / TM), dim3(256), 0, stream,
                       latents, emb, x2g, e2g, out);
}